// Round 10
// baseline (137.618 us; speedup 1.0000x reference)
//
#include <hip/hip_runtime.h>

// MCA linear attention, fp32. B=8, C=64, H=W=160, P=8 heads, d=8, N=25600.
#define NPIX  25600
#define NB    8
#define NCH   100    // pixel chunks per batch
#define CPX   256    // pixels per chunk (64 lanes x 4 px)
#define EPSV  1e-6f

// workspace layout (float offsets)
#define WS_WKVT  0        // [8 h][64 c][16]  (8 wk rows, 8 wv rows, transposed)
#define WS_WQT   8192     // [8 h][64 c][8]
#define WS_BKV   12288    // [8 h][16]
#define WS_BQ    12416    // [8 h][8]
#define WS_PART  12480    // [64 bh][100 ch][72]  (contiguous 72 per chunk)
#define WS_G     473280   // [8 b][64 pm][64 o]
#define WS_KSE   506048   // [8 b][8 p][8 m]

typedef float f32x2 __attribute__((ext_vector_type(2)));

__device__ __forceinline__ f32x2 pk_fma(f32x2 a, f32x2 b, f32x2 c) {
  return __builtin_elementwise_fma(a, b, c);    // -> v_pk_fma_f32
}

__device__ __forceinline__ float softplus_(float x) {
  // hw v_exp/v_log path; for x>20, log(1+e^x)==x to fp32 precision
  return (x > 20.0f) ? x : __logf(1.0f + __expf(x));
}

// DPP wave64 sum: row_shr 1/2/4/8 then row_bcast:15 (rows 1,3) and
// row_bcast:31 (rows 2,3). Full sum lands in lane 63. old=0 makes masked /
// invalid lanes contribute 0 regardless of bound_ctrl interpretation.
template <int CTRL, int RMASK>
__device__ __forceinline__ float dpp_add(float x) {
  int y = __builtin_amdgcn_update_dpp(0, __float_as_int(x), CTRL, RMASK, 0xf, false);
  return x + __int_as_float(y);
}
__device__ __forceinline__ float wave_sum63(float x) {
  x = dpp_add<0x111, 0xf>(x);   // row_shr:1
  x = dpp_add<0x112, 0xf>(x);   // row_shr:2
  x = dpp_add<0x114, 0xf>(x);   // row_shr:4
  x = dpp_add<0x118, 0xf>(x);   // row_shr:8
  x = dpp_add<0x142, 0xa>(x);   // row_bcast:15 -> rows 1,3
  x = dpp_add<0x143, 0xc>(x);   // row_bcast:31 -> rows 2,3
  return x;                     // lane 63 holds the wave total
}

// ---------------- kernel 0: pack weights/biases transposed ----------------
__global__ void k0_pack(const float* __restrict__ wq_high, const float* __restrict__ bq_high,
                        const float* __restrict__ wq_low,  const float* __restrict__ bq_low,
                        const float* __restrict__ wk, const float* __restrict__ bk,
                        const float* __restrict__ wv, const float* __restrict__ bv,
                        float* __restrict__ ws) {
  const int tid = threadIdx.x;
  for (int e = tid; e < 8192; e += 256) {        // wkvT[h][c][j]
    int j = e & 15, c = (e >> 4) & 63, h = e >> 10, m = j & 7;
    float v = (j < 8) ? wk[(h * 8 + m) * 64 + c] : wv[(h * 8 + m) * 64 + c];
    ws[WS_WKVT + e] = v;
  }
  for (int e = tid; e < 4096; e += 256) {        // wqT[h][c][m]
    int m = e & 7, c = (e >> 3) & 63, h = e >> 9;
    float v = (h < 4) ? wq_high[(h * 8 + m) * 64 + c]
                      : wq_low[((h - 4) * 8 + m) * 64 + c];
    ws[WS_WQT + e] = v;
  }
  for (int e = tid; e < 128; e += 256) {         // bkv[h][j]
    int j = e & 15, h = e >> 4, m = j & 7;
    ws[WS_BKV + e] = (j < 8) ? bk[h * 8 + m] : bv[h * 8 + m];
  }
  for (int e = tid; e < 64; e += 256) {          // bq[h][m]
    int m = e & 7, h = e >> 3;
    ws[WS_BQ + e] = (h < 4) ? bq_high[h * 8 + m] : bq_low[(h - 4) * 8 + m];
  }
}

// ---------------- kernel 1: k,v -> per-chunk partial attn/ksum ----------------
// 256 threads = 4 waves; block (chunk, b, half) -> wave w = head half*4+w.
// Lane owns 4 px as two f32x2 pairs; inner loop is v_pk_fma_f32 (2 FMA/instr,
// bit-exact fp32). Weights via wave-uniform s_loads (SGPR broadcast folds into
// VOP3P). Row-streaming + DPP reduce; no launch bounds; waves_per_eu relaxed.
__global__ __attribute__((amdgpu_waves_per_eu(1, 8)))
void k1_kv(const float* __restrict__ low,
           const float* __restrict__ ws,
           float* __restrict__ part) {
  const int b = blockIdx.y >> 1, half = blockIdx.y & 1, chunk = blockIdx.x;
  const int tid = threadIdx.x, lane = tid & 63;
  const int wu = __builtin_amdgcn_readfirstlane(half * 4 + (tid >> 6));
  const float* lowb = low + (size_t)b * 64 * NPIX + chunk * CPX;
  const float* wt = ws + WS_WKVT + wu * 1024;    // wave-uniform -> s_load
  const float* bias = ws + WS_BKV + wu * 16;
  f32x2 ka[8][2], va[8][2];
#pragma unroll
  for (int m = 0; m < 8; m++) {
    f32x2 bk2 = {bias[m], bias[m]};
    f32x2 bv2 = {bias[8 + m], bias[8 + m]};
    ka[m][0] = bk2; ka[m][1] = bk2;
    va[m][0] = bv2; va[m][1] = bv2;
  }
#pragma unroll 8
  for (int c = 0; c < 64; c++) {
    float4 x = reinterpret_cast<const float4*>(lowb + (size_t)c * NPIX)[lane];
    f32x2 x01 = {x.x, x.y}, x23 = {x.z, x.w};
    const float* wr = wt + c * 16;
#pragma unroll
    for (int m = 0; m < 8; m++) {
      f32x2 wk2 = {wr[m], wr[m]};
      f32x2 wv2 = {wr[8 + m], wr[8 + m]};
      ka[m][0] = pk_fma(wk2, x01, ka[m][0]);
      ka[m][1] = pk_fma(wk2, x23, ka[m][1]);
      va[m][0] = pk_fma(wv2, x01, va[m][0]);
      va[m][1] = pk_fma(wv2, x23, va[m][1]);
    }
  }
#pragma unroll
  for (int m = 0; m < 8; m++) {
    ka[m][0].x = softplus_(ka[m][0].x); ka[m][0].y = softplus_(ka[m][0].y);
    ka[m][1].x = softplus_(ka[m][1].x); ka[m][1].y = softplus_(ka[m][1].y);
  }
  float* pb = part + ((size_t)(b * 8 + wu) * NCH + chunk) * 72;
  // attn rows, streamed: pk products -> DPP reduce -> lane-63 float4 store
#pragma unroll
  for (int m = 0; m < 8; m++) {
    float r[8];
#pragma unroll
    for (int c = 0; c < 8; c++) {
      f32x2 p = pk_fma(ka[m][1], va[c][1], ka[m][0] * va[c][0]);
      r[c] = p.x + p.y;
    }
#pragma unroll
    for (int c = 0; c < 8; c++) r[c] = wave_sum63(r[c]);
    if (lane == 63) {
      reinterpret_cast<float4*>(&pb[m * 8])[0] = make_float4(r[0], r[1], r[2], r[3]);
      reinterpret_cast<float4*>(&pb[m * 8])[1] = make_float4(r[4], r[5], r[6], r[7]);
    }
  }
  // ksum row
  {
    float r[8];
#pragma unroll
    for (int m = 0; m < 8; m++) {
      f32x2 s2 = ka[m][0] + ka[m][1];
      r[m] = s2.x + s2.y;
    }
#pragma unroll
    for (int m = 0; m < 8; m++) r[m] = wave_sum63(r[m]);
    if (lane == 63) {
      reinterpret_cast<float4*>(&pb[64])[0] = make_float4(r[0], r[1], r[2], r[3]);
      reinterpret_cast<float4*>(&pb[64])[1] = make_float4(r[4], r[5], r[6], r[7]);
    }
  }
}

// ---------------- kernel 2: reduce partials, build G and ksumE ----------------
// 64 blocks (b*8+p) x 256 threads; chunk loop split 4-way across sub-waves.
__global__ void k2_g(const float* __restrict__ part, const float* __restrict__ wo,
                     float* __restrict__ ws) {
  const int b = blockIdx.x >> 3, p = blockIdx.x & 7;
  const int tid = threadIdx.x, lane = tid & 63, sub = tid >> 6;
  __shared__ float red[4][72];
  __shared__ float attnL[72];
  const float* src = part + (size_t)(b * 8 + p) * NCH * 72;
  float s0 = 0.0f, s1 = 0.0f;
  for (int ch = sub * (NCH / 4); ch < (sub + 1) * (NCH / 4); ch++) {
    s0 += src[ch * 72 + lane];
    if (lane < 8) s1 += src[ch * 72 + 64 + lane];
  }
  red[sub][lane] = s0;
  if (lane < 8) red[sub][64 + lane] = s1;
  __syncthreads();
  if (tid < 72) attnL[tid] = (red[0][tid] + red[1][tid]) + (red[2][tid] + red[3][tid]);
  __syncthreads();
  if (tid >= 64) {
    if (tid < 72) ws[WS_KSE + (b * 8 + p) * 8 + (tid - 64)] = attnL[tid] + EPSV;
    return;
  }
  const int o = tid;
  float wrow[8];
#pragma unroll
  for (int c = 0; c < 8; c++) wrow[c] = wo[o * 64 + p * 8 + c];
  float* Gp = ws + WS_G + (size_t)(b * 64 + p * 8) * 64;
#pragma unroll
  for (int m = 0; m < 8; m++) {
    float g = 0.0f;
#pragma unroll
    for (int c = 0; c < 8; c++) g = fmaf(attnL[m * 8 + c], wrow[c], g);
    Gp[m * 64 + o] = g;
  }
}

// ---------------- kernel 3: q, norm, fused out-projection ----------------
// 512 threads = 8 waves, lane owns 4 px as two f32x2 pairs; both GEMM phases
// use v_pk_fma_f32. Phase A: wave w -> qs for head w -> qsL. Phase B: wave w
// -> output channels [8w, 8w+8) (G via wave-uniform s_loads).
__global__ __attribute__((amdgpu_waves_per_eu(1, 8)))
void k3_main(const float* __restrict__ high,
             const float* __restrict__ low,
             const float* __restrict__ ws,
             const float* __restrict__ bo,
             float* __restrict__ out) {
  const int b = blockIdx.y, chunk = blockIdx.x;
  const int tid = threadIdx.x, lane = tid & 63;
  const int wu = __builtin_amdgcn_readfirstlane(tid >> 6);
  __shared__ float qsL[64 * CPX];                // [64 pm][256 px]
  const float* srcb = ((wu < 4) ? high : low) + (size_t)b * 64 * NPIX + chunk * CPX;
  const float* wq  = ws + WS_WQT + wu * 512;
  const float* bq  = ws + WS_BQ + wu * 8;
  const float* kse = ws + WS_KSE + (b * 8 + wu) * 8;
  const float* Gb  = ws + WS_G + (size_t)b * 4096 + wu * 8;
  f32x2 qa[8][2];
#pragma unroll
  for (int m = 0; m < 8; m++) {
    f32x2 b2 = {bq[m], bq[m]};
    qa[m][0] = b2; qa[m][1] = b2;
  }
#pragma unroll 8
  for (int c = 0; c < 64; c++) {
    float4 x = reinterpret_cast<const float4*>(srcb + (size_t)c * NPIX)[lane];
    f32x2 x01 = {x.x, x.y}, x23 = {x.z, x.w};
    const float* wr = wq + c * 8;
#pragma unroll
    for (int m = 0; m < 8; m++) {
      f32x2 w2 = {wr[m], wr[m]};
      qa[m][0] = pk_fma(w2, x01, qa[m][0]);
      qa[m][1] = pk_fma(w2, x23, qa[m][1]);
    }
  }
  f32x2 s01 = {0.0f, 0.0f}, s23 = {0.0f, 0.0f};
#pragma unroll
  for (int m = 0; m < 8; m++) {
    qa[m][0].x = softplus_(qa[m][0].x); qa[m][0].y = softplus_(qa[m][0].y);
    qa[m][1].x = softplus_(qa[m][1].x); qa[m][1].y = softplus_(qa[m][1].y);
    f32x2 k2 = {kse[m], kse[m]};
    s01 = pk_fma(qa[m][0], k2, s01);
    s23 = pk_fma(qa[m][1], k2, s23);
  }
  f32x2 r01 = {1.0f / s01.x, 1.0f / s01.y};
  f32x2 r23 = {1.0f / s23.x, 1.0f / s23.y};
#pragma unroll
  for (int m = 0; m < 8; m++) {
    f32x2 q01 = qa[m][0] * r01, q23 = qa[m][1] * r23;
    reinterpret_cast<float4*>(&qsL[(wu * 8 + m) * CPX])[lane] =
        make_float4(q01.x, q01.y, q23.x, q23.y);
  }
  __syncthreads();
  f32x2 acc[8][2];
#pragma unroll
  for (int j = 0; j < 8; j++) {
    f32x2 b2 = {bo[wu * 8 + j], bo[wu * 8 + j]};
    acc[j][0] = b2; acc[j][1] = b2;
  }
#pragma unroll 4
  for (int pm = 0; pm < 64; pm++) {
    float4 qv = reinterpret_cast<const float4*>(&qsL[pm * CPX])[lane];
    f32x2 q01 = {qv.x, qv.y}, q23 = {qv.z, qv.w};
    const float* gr = Gb + pm * 64;              // wave-uniform -> s_load
#pragma unroll
    for (int j = 0; j < 8; j++) {
      f32x2 g2 = {gr[j], gr[j]};
      acc[j][0] = pk_fma(g2, q01, acc[j][0]);
      acc[j][1] = pk_fma(g2, q23, acc[j][1]);
    }
  }
  float* ob = out + (size_t)(b * 64 + wu * 8) * NPIX + chunk * CPX;
#pragma unroll
  for (int j = 0; j < 8; j++) {
    reinterpret_cast<float4*>(ob + (size_t)j * NPIX)[lane] =
        make_float4(acc[j][0].x, acc[j][0].y, acc[j][1].x, acc[j][1].y);
  }
}

extern "C" void kernel_launch(void* const* d_in, const int* in_sizes, int n_in,
                              void* d_out, int out_size, void* d_ws, size_t ws_size,
                              hipStream_t stream) {
  const float* high    = (const float*)d_in[0];
  const float* low     = (const float*)d_in[1];
  const float* wq_high = (const float*)d_in[2];
  const float* bq_high = (const float*)d_in[3];
  const float* wq_low  = (const float*)d_in[4];
  const float* bq_low  = (const float*)d_in[5];
  const float* wk      = (const float*)d_in[6];
  const float* bk      = (const float*)d_in[7];
  const float* wv      = (const float*)d_in[8];
  const float* bv      = (const float*)d_in[9];
  const float* wo      = (const float*)d_in[10];
  const float* bo      = (const float*)d_in[11];
  float* ws  = (float*)d_ws;
  float* out = (float*)d_out;

  k0_pack<<<1, 256, 0, stream>>>(wq_high, bq_high, wq_low, bq_low, wk, bk, wv, bv, ws);
  dim3 grid1(NCH, NB * 2);
  k1_kv<<<grid1, 256, 0, stream>>>(low, ws, ws + WS_PART);
  k2_g<<<64, 256, 0, stream>>>(ws + WS_PART, wo, ws);
  dim3 grid3(NCH, NB);
  k3_main<<<grid3, 512, 0, stream>>>(high, low, ws, bo, out);
}